// Round 8
// baseline (897.978 us; speedup 1.0000x reference)
//
#include <hip/hip_runtime.h>

#define NN 100000
#define NE 1600000
#define NBK 196       // ceil(100000/512) dst buckets (512 nodes each)
#define CAP 10240     // per-bucket edge capacity
#define EPB 8192      // edges per block in k_bin
#define NWAVES 4096   // wave count for k_mlp (grid-stride, streaming)
#define RB 32         // stage-1 reduction blocks

// ---------------- pass 1: bin edges by dst>>9, packed (src<<9)|dst_local ----------------
__global__ __launch_bounds__(256) void k_bin(const int* __restrict__ src,
                                             const int* __restrict__ dst,
                                             int* __restrict__ gcnt,
                                             unsigned int* __restrict__ binned, int E) {
  __shared__ int bcnt[256];
  const int t = threadIdx.x;
  const int e0 = blockIdx.x * EPB;
  bcnt[t] = 0;
  __syncthreads();
  for (int i = 0; i < EPB; i += 256) {
    int e = e0 + i + t;
    if (e < E) atomicAdd(&bcnt[dst[e] >> 9], 1);
  }
  __syncthreads();
  if (t < NBK) {
    int c = bcnt[t];
    bcnt[t] = c ? atomicAdd(&gcnt[t], c) : 0;
  }
  __syncthreads();
  for (int i = 0; i < EPB; i += 256) {
    int e = e0 + i + t;
    if (e < E) {
      int d = dst[e];
      int b = d >> 9;
      int pos = atomicAdd(&bcnt[b], 1);
      if (pos < CAP) binned[(size_t)b * CAP + pos] = ((unsigned int)src[e] << 9) | (d & 511);
    }
  }
}

// ---------------- pass 2: per-bucket local CSR (block-local writes) ----------------
__global__ __launch_bounds__(512) void k_csr(const unsigned int* __restrict__ binned,
                                             const int* __restrict__ gcnt,
                                             int* __restrict__ rowbeg,
                                             int* __restrict__ rowend,
                                             int* __restrict__ eidx, int N) {
  __shared__ int hist[512];
  __shared__ int cur[512];
  const int t = threadIdx.x;
  const int b = blockIdx.x;
  const size_t base = (size_t)b * CAP;
  int cnt = gcnt[b];
  if (cnt > CAP) cnt = CAP;
  hist[t] = 0;
  __syncthreads();
  for (int e = t; e < cnt; e += 512) atomicAdd(&hist[binned[base + e] & 511], 1);
  __syncthreads();
  const int own = hist[t];
  for (int o = 1; o < 512; o <<= 1) {
    int x = (t >= o) ? hist[t - o] : 0;
    __syncthreads();
    hist[t] += x;
    __syncthreads();
  }
  const int incl = hist[t];
  const int excl = incl - own;
  const int node = b * 512 + t;
  if (node < N) {
    rowbeg[node] = (int)base + excl;
    rowend[node] = (int)base + incl;
  }
  cur[t] = excl;
  __syncthreads();
  for (int e = t; e < cnt; e += 512) {
    unsigned int pk = binned[base + e];
    int pos = atomicAdd(&cur[pk & 511], 1);
    eidx[base + pos] = (int)(pk >> 9);
  }
}

// ------- stage-1 reduction: P[nblk][128] f32 -> PB[RB][128] f64, fully coalesced -------
// threads read FULL rows (lane c = t&127 -> consecutive floats), 2 rows per iter.
__global__ __launch_bounds__(256) void k_red1(const float* __restrict__ P, int nblk,
                                              double* __restrict__ PB) {
  const int t = threadIdx.x;
  const int c = t & 127;
  const int half = t >> 7;  // 0 or 1
  const int j = blockIdx.x;
  double acc = 0.0;
  for (int r = j * 2 + half; r < nblk; r += RB * 2)
    acc += (double)P[(size_t)r * 128 + c];
  __shared__ double red[256];
  red[t] = acc;
  __syncthreads();
  if (t < 128) PB[(size_t)j * 128 + t] = red[t] + red[t + 128];
}

// ------- stage-2: finish reduction, emit BN affine LUT -------
__global__ __launch_bounds__(128) void k_red2(const double* __restrict__ PB,
                                              const float* __restrict__ g,
                                              const float* __restrict__ bt,
                                              double invN, float* __restrict__ aff) {
  const int t = threadIdx.x;  // 0..127
  double acc = 0.0;
  for (int j = 0; j < RB; ++j) acc += PB[(size_t)j * 128 + t];
  __shared__ double st[128];
  st[t] = acc;
  __syncthreads();
  if (t < 64) {
    double mu = st[t] * invN;
    double var = st[64 + t] * invN - mu * mu;
    double ai = (double)g[t] / sqrt(var + 1e-5);
    aff[t] = (float)ai;
    aff[64 + t] = (float)((double)bt[t] - ai * mu);
  }
}

__device__ __forceinline__ float rdl(float v, int l) {
  return __int_as_float(__builtin_amdgcn_readlane(__float_as_int(v), l));
}

// ========== fused gather + GEMM1: Z = (gathered,affined A) @ W1 + b1, + stats(Z) ==========
// ONE group (4 consecutive nodes) per wave; 16-lane sub-group per node; 25000 waves.
// Gathered row lands directly in the readlane-GEMM register layout.
// Per-wave independent epilogue (NO LDS, NO barriers) — occupancy-critical.
template <bool XFORM>
__global__ __launch_bounds__(256) void k_gmm(const float* __restrict__ In,
                                             const float* __restrict__ aff,
                                             const int* __restrict__ rowbeg,
                                             const int* __restrict__ rowend,
                                             const int* __restrict__ eidx,
                                             const float* __restrict__ W,
                                             const float* __restrict__ b,
                                             float* __restrict__ Out,
                                             float* __restrict__ P, int N) {
  const int lane = threadIdx.x & 63;
  const int li = lane & 15;
  const int wid = (blockIdx.x * 256 + threadIdx.x) >> 6;  // = group index
  const int G = N >> 2;  // N % 4 == 0
  if (wid >= G) return;

  const int node = wid * 4 + (lane >> 4);
  const int beg = rowbeg[node], end = rowend[node];

  float w[64];
#pragma unroll
  for (int k = 0; k < 64; ++k) w[k] = W[k * 64 + lane];
  const float bias = b[lane];

  float4 fa = make_float4(1.f, 1.f, 1.f, 1.f);
  float4 fd = make_float4(0.f, 0.f, 0.f, 0.f);
  if (XFORM) {
    fa = *(const float4*)(aff + li * 4);
    fd = *(const float4*)(aff + 64 + li * 4);
  }

  float4 s = *(const float4*)(In + (size_t)node * 64 + li * 4);  // self (eps=0)
  float4 s2 = make_float4(0.f, 0.f, 0.f, 0.f);
  int i = beg;
  for (; i + 4 <= end; i += 4) {
    const int e0 = eidx[i], e1 = eidx[i + 1], e2 = eidx[i + 2], e3 = eidx[i + 3];
    const float4 v0 = *(const float4*)(In + (size_t)e0 * 64 + li * 4);
    const float4 v1 = *(const float4*)(In + (size_t)e1 * 64 + li * 4);
    const float4 v2 = *(const float4*)(In + (size_t)e2 * 64 + li * 4);
    const float4 v3 = *(const float4*)(In + (size_t)e3 * 64 + li * 4);
    s.x += v0.x + v1.x; s.y += v0.y + v1.y; s.z += v0.z + v1.z; s.w += v0.w + v1.w;
    s2.x += v2.x + v3.x; s2.y += v2.y + v3.y; s2.z += v2.z + v3.z; s2.w += v2.w + v3.w;
  }
  for (; i < end; ++i) {
    const float4 v = *(const float4*)(In + (size_t)eidx[i] * 64 + li * 4);
    s.x += v.x; s.y += v.y; s.z += v.z; s.w += v.w;
  }
  s.x += s2.x; s.y += s2.y; s.z += s2.z; s.w += s2.w;
  if (XFORM) {
    const float cnt = (float)(end - beg + 1);
    s.x = fmaf(fa.x, s.x, cnt * fd.x);
    s.y = fmaf(fa.y, s.y, cnt * fd.y);
    s.z = fmaf(fa.z, s.z, cnt * fd.z);
    s.w = fmaf(fa.w, s.w, cnt * fd.w);
  }
  const float a4[4] = {s.x, s.y, s.z, s.w};

  float acc0 = bias, acc1 = bias, acc2 = bias, acc3 = bias;
#pragma unroll
  for (int k = 0; k < 64; ++k) {
    const float ak = a4[k & 3];
    const int sl = k >> 2;
    acc0 = fmaf(rdl(ak, sl), w[k], acc0);
    acc1 = fmaf(rdl(ak, 16 + sl), w[k], acc1);
    acc2 = fmaf(rdl(ak, 32 + sl), w[k], acc2);
    acc3 = fmaf(rdl(ak, 48 + sl), w[k], acc3);
  }
  const int r0 = wid * 4;
  Out[(size_t)(r0 + 0) * 64 + lane] = acc0;
  Out[(size_t)(r0 + 1) * 64 + lane] = acc1;
  Out[(size_t)(r0 + 2) * 64 + lane] = acc2;
  Out[(size_t)(r0 + 3) * 64 + lane] = acc3;

  float sc = acc0 + acc1 + acc2 + acc3;
  float qc = 0.f;
  qc = fmaf(acc0, acc0, qc);
  qc = fmaf(acc1, acc1, qc);
  qc = fmaf(acc2, acc2, qc);
  qc = fmaf(acc3, acc3, qc);
  P[(size_t)wid * 128 + lane] = sc;
  P[(size_t)wid * 128 + 64 + lane] = qc;
}

// ========== register-resident GEMM2 (per-wave epilogue, no LDS/barriers) ==========
// MODE 1: relu(out), store, stats(relu)   [inner layers]
// MODE 3: log_softmax(out) -> store        [final layer]
template <int OUTC, int MODE>
__global__ __launch_bounds__(256) void k_mlp(const float* __restrict__ In,
                                             const float* __restrict__ aff,
                                             const float* __restrict__ W,
                                             const float* __restrict__ b,
                                             float* __restrict__ Out,
                                             float* __restrict__ P, int N) {
  const int lane = threadIdx.x & 63;
  const int wid = (blockIdx.x * 256 + threadIdx.x) >> 6;
  const int nw = NWAVES;
  const int G = N >> 2;

  const int cc = (lane < OUTC) ? lane : 0;
  float w[64];
#pragma unroll
  for (int k = 0; k < 64; ++k) w[k] = W[k * OUTC + cc];
  const float bias = b[cc];

  const float4 fa = *(const float4*)(aff + (lane & 15) * 4);
  const float4 fd = *(const float4*)(aff + 64 + (lane & 15) * 4);

  float sc = 0.f, qc = 0.f;

  int g = wid;
  float4 av = make_float4(0.f, 0.f, 0.f, 0.f);
  if (g < G) av = *(const float4*)(In + (size_t)g * 256 + lane * 4);
  for (; g < G; g += nw) {
    const int gn = g + nw;
    float4 nx = make_float4(0.f, 0.f, 0.f, 0.f);
    if (gn < G) nx = *(const float4*)(In + (size_t)gn * 256 + lane * 4);

    float4 v = av;
    v.x = fmaxf(fmaf(fa.x, v.x, fd.x), 0.f);
    v.y = fmaxf(fmaf(fa.y, v.y, fd.y), 0.f);
    v.z = fmaxf(fmaf(fa.z, v.z, fd.z), 0.f);
    v.w = fmaxf(fmaf(fa.w, v.w, fd.w), 0.f);
    const float a4[4] = {v.x, v.y, v.z, v.w};

    float acc0 = bias, acc1 = bias, acc2 = bias, acc3 = bias;
#pragma unroll
    for (int k = 0; k < 64; ++k) {
      const float ak = a4[k & 3];
      const int sl = k >> 2;
      acc0 = fmaf(rdl(ak, sl), w[k], acc0);
      acc1 = fmaf(rdl(ak, 16 + sl), w[k], acc1);
      acc2 = fmaf(rdl(ak, 32 + sl), w[k], acc2);
      acc3 = fmaf(rdl(ak, 48 + sl), w[k], acc3);
    }

    const int r0 = g * 4;
    if (MODE == 1) {
      const float o0 = fmaxf(acc0, 0.f), o1 = fmaxf(acc1, 0.f);
      const float o2 = fmaxf(acc2, 0.f), o3 = fmaxf(acc3, 0.f);
      Out[(size_t)(r0 + 0) * OUTC + lane] = o0;
      Out[(size_t)(r0 + 1) * OUTC + lane] = o1;
      Out[(size_t)(r0 + 2) * OUTC + lane] = o2;
      Out[(size_t)(r0 + 3) * OUTC + lane] = o3;
      sc += o0 + o1 + o2 + o3;
      qc = fmaf(o0, o0, qc);
      qc = fmaf(o1, o1, qc);
      qc = fmaf(o2, o2, qc);
      qc = fmaf(o3, o3, qc);
    } else {  // MODE 3: log_softmax over OUTC cols (lanes >= OUTC masked out)
      float m0 = (lane < OUTC) ? acc0 : -1e30f;
      float m1 = (lane < OUTC) ? acc1 : -1e30f;
      float m2 = (lane < OUTC) ? acc2 : -1e30f;
      float m3 = (lane < OUTC) ? acc3 : -1e30f;
#pragma unroll
      for (int off = 32; off; off >>= 1) {
        m0 = fmaxf(m0, __shfl_xor(m0, off));
        m1 = fmaxf(m1, __shfl_xor(m1, off));
        m2 = fmaxf(m2, __shfl_xor(m2, off));
        m3 = fmaxf(m3, __shfl_xor(m3, off));
      }
      float s0 = (lane < OUTC) ? expf(acc0 - m0) : 0.f;
      float s1 = (lane < OUTC) ? expf(acc1 - m1) : 0.f;
      float s2 = (lane < OUTC) ? expf(acc2 - m2) : 0.f;
      float s3 = (lane < OUTC) ? expf(acc3 - m3) : 0.f;
#pragma unroll
      for (int off = 32; off; off >>= 1) {
        s0 += __shfl_xor(s0, off);
        s1 += __shfl_xor(s1, off);
        s2 += __shfl_xor(s2, off);
        s3 += __shfl_xor(s3, off);
      }
      if (lane < OUTC) {
        Out[(size_t)(r0 + 0) * OUTC + lane] = acc0 - (m0 + logf(s0));
        Out[(size_t)(r0 + 1) * OUTC + lane] = acc1 - (m1 + logf(s1));
        Out[(size_t)(r0 + 2) * OUTC + lane] = acc2 - (m2 + logf(s2));
        Out[(size_t)(r0 + 3) * OUTC + lane] = acc3 - (m3 + logf(s3));
      }
    }
    av = nx;
  }

  if (MODE == 1) {
    P[(size_t)wid * 128 + lane] = sc;
    P[(size_t)wid * 128 + 64 + lane] = qc;
  }
}

extern "C" void kernel_launch(void* const* d_in, const int* in_sizes, int n_in,
                              void* d_out, int out_size, void* d_ws, size_t ws_size,
                              hipStream_t stream) {
  const float* x = (const float*)d_in[0];
  const int* src = (const int*)d_in[1];
  const int* dst = (const int*)d_in[2];
  const float *W1[3], *b1[3], *g[3], *bt[3], *W2[3], *b2[3];
  for (int i = 0; i < 3; ++i) {
    W1[i] = (const float*)d_in[3 + i * 6 + 0];
    b1[i] = (const float*)d_in[3 + i * 6 + 1];
    g[i] = (const float*)d_in[3 + i * 6 + 2];
    bt[i] = (const float*)d_in[3 + i * 6 + 3];
    W2[i] = (const float*)d_in[3 + i * 6 + 4];
    b2[i] = (const float*)d_in[3 + i * 6 + 5];
  }
  const float* bng[2] = {(const float*)d_in[21], (const float*)d_in[23]};
  const float* bnb[2] = {(const float*)d_in[22], (const float*)d_in[24]};

  const int N = NN, E = NE;
  const size_t N64 = (size_t)N * 64;
  const int G = N / 4;               // 25000 groups (1 per wave in k_gmm)
  const int ggmm = (G + 3) / 4;      // 6250 blocks
  const int gmlp = NWAVES / 4;       // 1024 blocks (grid-stride)

  // workspace layout (~85 MB)
  char* p = (char*)d_ws;
  float* B = (float*)p; p += N64 * 4;            // z buffer
  float* C = (float*)p; p += N64 * 4;            // relu(h) buffer
  int* gcnt = (int*)p; p += 256 * 4;             // bucket counters (memset)
  float* aff = (float*)p; p += 128 * 4;          // BN affine LUT (a[64], d[64])
  float* P = (float*)p; p += (size_t)G * 128 * 4;      // per-wave column partials (12.8MB)
  double* PB = (double*)p; p += (size_t)RB * 128 * 8;  // stage-1 reduction out (32KB)
  int* rowbeg = (int*)p; p += (size_t)N * 4;
  int* rowend = (int*)p; p += (size_t)N * 4;
  unsigned int* binned = (unsigned int*)p; p += (size_t)NBK * CAP * 4;
  int* eidx = (int*)p; p += (size_t)NBK * CAP * 4;

  const double invN = 1.0 / (double)N;

  hipMemsetAsync(gcnt, 0, 256 * 4, stream);

  // ---- CSR build (bucketed counting sort, block-local writes) ----
  k_bin<<<(E + EPB - 1) / EPB, 256, 0, stream>>>(src, dst, gcnt, binned, E);
  k_csr<<<NBK, 512, 0, stream>>>(binned, gcnt, rowbeg, rowend, eidx, N);

  // ---- layer 0 (input = x, no affine on gather) ----
  k_gmm<false><<<ggmm, 256, 0, stream>>>(x, nullptr, rowbeg, rowend, eidx, W1[0], b1[0], B, P, N);
  k_red1<<<RB, 256, 0, stream>>>(P, G, PB);
  k_red2<<<1, 128, 0, stream>>>(PB, g[0], bt[0], invN, aff);
  k_mlp<64, 1><<<gmlp, 256, 0, stream>>>(B, aff, W2[0], b2[0], C, P, N);
  k_red1<<<RB, 256, 0, stream>>>(P, NWAVES, PB);
  k_red2<<<1, 128, 0, stream>>>(PB, bng[0], bnb[0], invN, aff);

  // ---- layer 1 ----
  k_gmm<true><<<ggmm, 256, 0, stream>>>(C, aff, rowbeg, rowend, eidx, W1[1], b1[1], B, P, N);
  k_red1<<<RB, 256, 0, stream>>>(P, G, PB);
  k_red2<<<1, 128, 0, stream>>>(PB, g[1], bt[1], invN, aff);
  k_mlp<64, 1><<<gmlp, 256, 0, stream>>>(B, aff, W2[1], b2[1], C, P, N);
  k_red1<<<RB, 256, 0, stream>>>(P, NWAVES, PB);
  k_red2<<<1, 128, 0, stream>>>(PB, bng[1], bnb[1], invN, aff);

  // ---- layer 2 (final: fused log_softmax) ----
  k_gmm<true><<<ggmm, 256, 0, stream>>>(C, aff, rowbeg, rowend, eidx, W1[2], b1[2], B, P, N);
  k_red1<<<RB, 256, 0, stream>>>(P, G, PB);
  k_red2<<<1, 128, 0, stream>>>(PB, g[2], bt[2], invN, aff);
  k_mlp<40, 3><<<gmlp, 256, 0, stream>>>(B, aff, W2[2], b2[2], (float*)d_out, nullptr, N);
}

// Round 9
// 571.528 us; speedup vs baseline: 1.5712x; 1.5712x over previous
//
#include <hip/hip_runtime.h>

#define NN 100000
#define NE 1600000
#define NBK 196       // ceil(100000/512) dst buckets (512 nodes each)
#define CAP 10240     // per-bucket edge capacity
#define EPB 8192      // edges per block in k_bin
#define NWAVES 4096   // wave count for k_mlp (grid-stride, streaming)
#define RB 128        // stage-1 reduction blocks

// ---------------- pass 1: bin edges by dst>>9, packed (src<<9)|dst_local ----------------
__global__ __launch_bounds__(256) void k_bin(const int* __restrict__ src,
                                             const int* __restrict__ dst,
                                             int* __restrict__ gcnt,
                                             unsigned int* __restrict__ binned, int E) {
  __shared__ int bcnt[256];
  const int t = threadIdx.x;
  const int e0 = blockIdx.x * EPB;
  bcnt[t] = 0;
  __syncthreads();
  for (int i = 0; i < EPB; i += 256) {
    int e = e0 + i + t;
    if (e < E) atomicAdd(&bcnt[dst[e] >> 9], 1);
  }
  __syncthreads();
  if (t < NBK) {
    int c = bcnt[t];
    bcnt[t] = c ? atomicAdd(&gcnt[t], c) : 0;
  }
  __syncthreads();
  for (int i = 0; i < EPB; i += 256) {
    int e = e0 + i + t;
    if (e < E) {
      int d = dst[e];
      int b = d >> 9;
      int pos = atomicAdd(&bcnt[b], 1);
      if (pos < CAP) binned[(size_t)b * CAP + pos] = ((unsigned int)src[e] << 9) | (d & 511);
    }
  }
}

// ---------------- pass 2: per-bucket local CSR (block-local writes) ----------------
__global__ __launch_bounds__(512) void k_csr(const unsigned int* __restrict__ binned,
                                             const int* __restrict__ gcnt,
                                             int* __restrict__ rowbeg,
                                             int* __restrict__ rowend,
                                             int* __restrict__ eidx, int N) {
  __shared__ int hist[512];
  __shared__ int cur[512];
  const int t = threadIdx.x;
  const int b = blockIdx.x;
  const size_t base = (size_t)b * CAP;
  int cnt = gcnt[b];
  if (cnt > CAP) cnt = CAP;
  hist[t] = 0;
  __syncthreads();
  for (int e = t; e < cnt; e += 512) atomicAdd(&hist[binned[base + e] & 511], 1);
  __syncthreads();
  const int own = hist[t];
  for (int o = 1; o < 512; o <<= 1) {
    int x = (t >= o) ? hist[t - o] : 0;
    __syncthreads();
    hist[t] += x;
    __syncthreads();
  }
  const int incl = hist[t];
  const int excl = incl - own;
  const int node = b * 512 + t;
  if (node < N) {
    rowbeg[node] = (int)base + excl;
    rowend[node] = (int)base + incl;
  }
  cur[t] = excl;
  __syncthreads();
  for (int e = t; e < cnt; e += 512) {
    unsigned int pk = binned[base + e];
    int pos = atomicAdd(&cur[pk & 511], 1);
    eidx[base + pos] = (int)(pk >> 9);
  }
}

// ------- stage-1 reduction: P[nblk][128] f32 -> PB[RB][128] f64 -------
// coalesced (lane c -> consecutive floats) + ILP-4 (independent accumulators).
__global__ __launch_bounds__(256) void k_red1(const float* __restrict__ P, int nblk,
                                              double* __restrict__ PB) {
  const int t = threadIdx.x;
  const int c = t & 127;
  const int half = t >> 7;  // 0 or 1
  const int j = blockIdx.x;
  const int STR = RB * 2;   // 256 rows per sweep
  double a0 = 0.0, a1 = 0.0, a2 = 0.0, a3 = 0.0;
  int r = j * 2 + half;
  for (; r + 3 * STR < nblk; r += 4 * STR) {
    a0 += (double)P[(size_t)r * 128 + c];
    a1 += (double)P[(size_t)(r + STR) * 128 + c];
    a2 += (double)P[(size_t)(r + 2 * STR) * 128 + c];
    a3 += (double)P[(size_t)(r + 3 * STR) * 128 + c];
  }
  for (; r < nblk; r += STR) a0 += (double)P[(size_t)r * 128 + c];
  double acc = (a0 + a1) + (a2 + a3);
  __shared__ double red[256];
  red[t] = acc;
  __syncthreads();
  if (t < 128) PB[(size_t)j * 128 + t] = red[t] + red[t + 128];
}

// ------- stage-2: finish reduction (ILP-4), emit BN affine LUT -------
__global__ __launch_bounds__(256) void k_red2(const double* __restrict__ PB,
                                              const float* __restrict__ g,
                                              const float* __restrict__ bt,
                                              double invN, float* __restrict__ aff) {
  const int t = threadIdx.x;
  const int c = t & 127;
  const int half = t >> 7;
  double a0 = 0.0, a1 = 0.0, a2 = 0.0, a3 = 0.0;
  int j = half;
  for (; j + 6 < RB; j += 8) {
    a0 += PB[(size_t)j * 128 + c];
    a1 += PB[(size_t)(j + 2) * 128 + c];
    a2 += PB[(size_t)(j + 4) * 128 + c];
    a3 += PB[(size_t)(j + 6) * 128 + c];
  }
  for (; j < RB; j += 2) a0 += PB[(size_t)j * 128 + c];
  __shared__ double st[256];
  st[t] = (a0 + a1) + (a2 + a3);
  __syncthreads();
  if (t < 128) st[t] = st[t] + st[t + 128];
  __syncthreads();
  if (t < 64) {
    double mu = st[t] * invN;
    double var = st[64 + t] * invN - mu * mu;
    double ai = (double)g[t] / sqrt(var + 1e-5);
    aff[t] = (float)ai;
    aff[64 + t] = (float)((double)bt[t] - ai * mu);
  }
}

__device__ __forceinline__ float rdl(float v, int l) {
  return __int_as_float(__builtin_amdgcn_readlane(__float_as_int(v), l));
}

// ========== fused gather + GEMM1: Z = (gathered,affined A) @ W1 + b1, + stats(Z) ==========
// ONE group (4 consecutive nodes) per wave; 16-lane sub-group per node; 25000 waves.
// Gathered row lands directly in the readlane-GEMM register layout.
// Per-wave independent epilogue (NO LDS, NO barriers) — occupancy-critical.
template <bool XFORM>
__global__ __launch_bounds__(256) void k_gmm(const float* __restrict__ In,
                                             const float* __restrict__ aff,
                                             const int* __restrict__ rowbeg,
                                             const int* __restrict__ rowend,
                                             const int* __restrict__ eidx,
                                             const float* __restrict__ W,
                                             const float* __restrict__ b,
                                             float* __restrict__ Out,
                                             float* __restrict__ P, int N) {
  const int lane = threadIdx.x & 63;
  const int li = lane & 15;
  const int wid = (blockIdx.x * 256 + threadIdx.x) >> 6;  // = group index
  const int G = N >> 2;  // N % 4 == 0
  if (wid >= G) return;

  const int node = wid * 4 + (lane >> 4);
  const int beg = rowbeg[node], end = rowend[node];

  float w[64];
#pragma unroll
  for (int k = 0; k < 64; ++k) w[k] = W[k * 64 + lane];
  const float bias = b[lane];

  float4 fa = make_float4(1.f, 1.f, 1.f, 1.f);
  float4 fd = make_float4(0.f, 0.f, 0.f, 0.f);
  if (XFORM) {
    fa = *(const float4*)(aff + li * 4);
    fd = *(const float4*)(aff + 64 + li * 4);
  }

  float4 s = *(const float4*)(In + (size_t)node * 64 + li * 4);  // self (eps=0)
  float4 s2 = make_float4(0.f, 0.f, 0.f, 0.f);
  int i = beg;
  for (; i + 4 <= end; i += 4) {
    const int e0 = eidx[i], e1 = eidx[i + 1], e2 = eidx[i + 2], e3 = eidx[i + 3];
    const float4 v0 = *(const float4*)(In + (size_t)e0 * 64 + li * 4);
    const float4 v1 = *(const float4*)(In + (size_t)e1 * 64 + li * 4);
    const float4 v2 = *(const float4*)(In + (size_t)e2 * 64 + li * 4);
    const float4 v3 = *(const float4*)(In + (size_t)e3 * 64 + li * 4);
    s.x += v0.x + v1.x; s.y += v0.y + v1.y; s.z += v0.z + v1.z; s.w += v0.w + v1.w;
    s2.x += v2.x + v3.x; s2.y += v2.y + v3.y; s2.z += v2.z + v3.z; s2.w += v2.w + v3.w;
  }
  for (; i < end; ++i) {
    const float4 v = *(const float4*)(In + (size_t)eidx[i] * 64 + li * 4);
    s.x += v.x; s.y += v.y; s.z += v.z; s.w += v.w;
  }
  s.x += s2.x; s.y += s2.y; s.z += s2.z; s.w += s2.w;
  if (XFORM) {
    const float cnt = (float)(end - beg + 1);
    s.x = fmaf(fa.x, s.x, cnt * fd.x);
    s.y = fmaf(fa.y, s.y, cnt * fd.y);
    s.z = fmaf(fa.z, s.z, cnt * fd.z);
    s.w = fmaf(fa.w, s.w, cnt * fd.w);
  }
  const float a4[4] = {s.x, s.y, s.z, s.w};

  float acc0 = bias, acc1 = bias, acc2 = bias, acc3 = bias;
#pragma unroll
  for (int k = 0; k < 64; ++k) {
    const float ak = a4[k & 3];
    const int sl = k >> 2;
    acc0 = fmaf(rdl(ak, sl), w[k], acc0);
    acc1 = fmaf(rdl(ak, 16 + sl), w[k], acc1);
    acc2 = fmaf(rdl(ak, 32 + sl), w[k], acc2);
    acc3 = fmaf(rdl(ak, 48 + sl), w[k], acc3);
  }
  const int r0 = wid * 4;
  Out[(size_t)(r0 + 0) * 64 + lane] = acc0;
  Out[(size_t)(r0 + 1) * 64 + lane] = acc1;
  Out[(size_t)(r0 + 2) * 64 + lane] = acc2;
  Out[(size_t)(r0 + 3) * 64 + lane] = acc3;

  float sc = acc0 + acc1 + acc2 + acc3;
  float qc = 0.f;
  qc = fmaf(acc0, acc0, qc);
  qc = fmaf(acc1, acc1, qc);
  qc = fmaf(acc2, acc2, qc);
  qc = fmaf(acc3, acc3, qc);
  P[(size_t)wid * 128 + lane] = sc;
  P[(size_t)wid * 128 + 64 + lane] = qc;
}

// ========== register-resident GEMM2 (per-wave epilogue, no LDS/barriers) ==========
// MODE 1: relu(out), store, stats(relu)   [inner layers]
// MODE 3: log_softmax(out) -> store        [final layer]
template <int OUTC, int MODE>
__global__ __launch_bounds__(256) void k_mlp(const float* __restrict__ In,
                                             const float* __restrict__ aff,
                                             const float* __restrict__ W,
                                             const float* __restrict__ b,
                                             float* __restrict__ Out,
                                             float* __restrict__ P, int N) {
  const int lane = threadIdx.x & 63;
  const int wid = (blockIdx.x * 256 + threadIdx.x) >> 6;
  const int nw = NWAVES;
  const int G = N >> 2;

  const int cc = (lane < OUTC) ? lane : 0;
  float w[64];
#pragma unroll
  for (int k = 0; k < 64; ++k) w[k] = W[k * OUTC + cc];
  const float bias = b[cc];

  const float4 fa = *(const float4*)(aff + (lane & 15) * 4);
  const float4 fd = *(const float4*)(aff + 64 + (lane & 15) * 4);

  float sc = 0.f, qc = 0.f;

  int g = wid;
  float4 av = make_float4(0.f, 0.f, 0.f, 0.f);
  if (g < G) av = *(const float4*)(In + (size_t)g * 256 + lane * 4);
  for (; g < G; g += nw) {
    const int gn = g + nw;
    float4 nx = make_float4(0.f, 0.f, 0.f, 0.f);
    if (gn < G) nx = *(const float4*)(In + (size_t)gn * 256 + lane * 4);

    float4 v = av;
    v.x = fmaxf(fmaf(fa.x, v.x, fd.x), 0.f);
    v.y = fmaxf(fmaf(fa.y, v.y, fd.y), 0.f);
    v.z = fmaxf(fmaf(fa.z, v.z, fd.z), 0.f);
    v.w = fmaxf(fmaf(fa.w, v.w, fd.w), 0.f);
    const float a4[4] = {v.x, v.y, v.z, v.w};

    float acc0 = bias, acc1 = bias, acc2 = bias, acc3 = bias;
#pragma unroll
    for (int k = 0; k < 64; ++k) {
      const float ak = a4[k & 3];
      const int sl = k >> 2;
      acc0 = fmaf(rdl(ak, sl), w[k], acc0);
      acc1 = fmaf(rdl(ak, 16 + sl), w[k], acc1);
      acc2 = fmaf(rdl(ak, 32 + sl), w[k], acc2);
      acc3 = fmaf(rdl(ak, 48 + sl), w[k], acc3);
    }

    const int r0 = g * 4;
    if (MODE == 1) {
      const float o0 = fmaxf(acc0, 0.f), o1 = fmaxf(acc1, 0.f);
      const float o2 = fmaxf(acc2, 0.f), o3 = fmaxf(acc3, 0.f);
      Out[(size_t)(r0 + 0) * OUTC + lane] = o0;
      Out[(size_t)(r0 + 1) * OUTC + lane] = o1;
      Out[(size_t)(r0 + 2) * OUTC + lane] = o2;
      Out[(size_t)(r0 + 3) * OUTC + lane] = o3;
      sc += o0 + o1 + o2 + o3;
      qc = fmaf(o0, o0, qc);
      qc = fmaf(o1, o1, qc);
      qc = fmaf(o2, o2, qc);
      qc = fmaf(o3, o3, qc);
    } else {  // MODE 3: log_softmax over OUTC cols (lanes >= OUTC masked out)
      float m0 = (lane < OUTC) ? acc0 : -1e30f;
      float m1 = (lane < OUTC) ? acc1 : -1e30f;
      float m2 = (lane < OUTC) ? acc2 : -1e30f;
      float m3 = (lane < OUTC) ? acc3 : -1e30f;
#pragma unroll
      for (int off = 32; off; off >>= 1) {
        m0 = fmaxf(m0, __shfl_xor(m0, off));
        m1 = fmaxf(m1, __shfl_xor(m1, off));
        m2 = fmaxf(m2, __shfl_xor(m2, off));
        m3 = fmaxf(m3, __shfl_xor(m3, off));
      }
      float s0 = (lane < OUTC) ? expf(acc0 - m0) : 0.f;
      float s1 = (lane < OUTC) ? expf(acc1 - m1) : 0.f;
      float s2 = (lane < OUTC) ? expf(acc2 - m2) : 0.f;
      float s3 = (lane < OUTC) ? expf(acc3 - m3) : 0.f;
#pragma unroll
      for (int off = 32; off; off >>= 1) {
        s0 += __shfl_xor(s0, off);
        s1 += __shfl_xor(s1, off);
        s2 += __shfl_xor(s2, off);
        s3 += __shfl_xor(s3, off);
      }
      if (lane < OUTC) {
        Out[(size_t)(r0 + 0) * OUTC + lane] = acc0 - (m0 + logf(s0));
        Out[(size_t)(r0 + 1) * OUTC + lane] = acc1 - (m1 + logf(s1));
        Out[(size_t)(r0 + 2) * OUTC + lane] = acc2 - (m2 + logf(s2));
        Out[(size_t)(r0 + 3) * OUTC + lane] = acc3 - (m3 + logf(s3));
      }
    }
    av = nx;
  }

  if (MODE == 1) {
    P[(size_t)wid * 128 + lane] = sc;
    P[(size_t)wid * 128 + 64 + lane] = qc;
  }
}

extern "C" void kernel_launch(void* const* d_in, const int* in_sizes, int n_in,
                              void* d_out, int out_size, void* d_ws, size_t ws_size,
                              hipStream_t stream) {
  const float* x = (const float*)d_in[0];
  const int* src = (const int*)d_in[1];
  const int* dst = (const int*)d_in[2];
  const float *W1[3], *b1[3], *g[3], *bt[3], *W2[3], *b2[3];
  for (int i = 0; i < 3; ++i) {
    W1[i] = (const float*)d_in[3 + i * 6 + 0];
    b1[i] = (const float*)d_in[3 + i * 6 + 1];
    g[i] = (const float*)d_in[3 + i * 6 + 2];
    bt[i] = (const float*)d_in[3 + i * 6 + 3];
    W2[i] = (const float*)d_in[3 + i * 6 + 4];
    b2[i] = (const float*)d_in[3 + i * 6 + 5];
  }
  const float* bng[2] = {(const float*)d_in[21], (const float*)d_in[23]};
  const float* bnb[2] = {(const float*)d_in[22], (const float*)d_in[24]};

  const int N = NN, E = NE;
  const size_t N64 = (size_t)N * 64;
  const int G = N / 4;               // 25000 groups (1 per wave in k_gmm)
  const int ggmm = (G + 3) / 4;      // 6250 blocks
  const int gmlp = NWAVES / 4;       // 1024 blocks (grid-stride)

  // workspace layout (~85 MB)
  char* p = (char*)d_ws;
  float* B = (float*)p; p += N64 * 4;            // z buffer
  float* C = (float*)p; p += N64 * 4;            // relu(h) buffer
  int* gcnt = (int*)p; p += 256 * 4;             // bucket counters (memset)
  float* aff = (float*)p; p += 128 * 4;          // BN affine LUT (a[64], d[64])
  float* P = (float*)p; p += (size_t)G * 128 * 4;      // per-wave column partials (12.8MB)
  double* PB = (double*)p; p += (size_t)RB * 128 * 8;  // stage-1 reduction out (128KB)
  int* rowbeg = (int*)p; p += (size_t)N * 4;
  int* rowend = (int*)p; p += (size_t)N * 4;
  unsigned int* binned = (unsigned int*)p; p += (size_t)NBK * CAP * 4;
  int* eidx = (int*)p; p += (size_t)NBK * CAP * 4;

  const double invN = 1.0 / (double)N;

  hipMemsetAsync(gcnt, 0, 256 * 4, stream);

  // ---- CSR build (bucketed counting sort, block-local writes) ----
  k_bin<<<(E + EPB - 1) / EPB, 256, 0, stream>>>(src, dst, gcnt, binned, E);
  k_csr<<<NBK, 512, 0, stream>>>(binned, gcnt, rowbeg, rowend, eidx, N);

  // ---- layer 0 (input = x, no affine on gather) ----
  k_gmm<false><<<ggmm, 256, 0, stream>>>(x, nullptr, rowbeg, rowend, eidx, W1[0], b1[0], B, P, N);
  k_red1<<<RB, 256, 0, stream>>>(P, G, PB);
  k_red2<<<1, 256, 0, stream>>>(PB, g[0], bt[0], invN, aff);
  k_mlp<64, 1><<<gmlp, 256, 0, stream>>>(B, aff, W2[0], b2[0], C, P, N);
  k_red1<<<RB, 256, 0, stream>>>(P, NWAVES, PB);
  k_red2<<<1, 256, 0, stream>>>(PB, bng[0], bnb[0], invN, aff);

  // ---- layer 1 ----
  k_gmm<true><<<ggmm, 256, 0, stream>>>(C, aff, rowbeg, rowend, eidx, W1[1], b1[1], B, P, N);
  k_red1<<<RB, 256, 0, stream>>>(P, G, PB);
  k_red2<<<1, 256, 0, stream>>>(PB, g[1], bt[1], invN, aff);
  k_mlp<64, 1><<<gmlp, 256, 0, stream>>>(B, aff, W2[1], b2[1], C, P, N);
  k_red1<<<RB, 256, 0, stream>>>(P, NWAVES, PB);
  k_red2<<<1, 256, 0, stream>>>(PB, bng[1], bnb[1], invN, aff);

  // ---- layer 2 (final: fused log_softmax) ----
  k_gmm<true><<<ggmm, 256, 0, stream>>>(C, aff, rowbeg, rowend, eidx, W1[2], b1[2], B, P, N);
  k_red1<<<RB, 256, 0, stream>>>(P, G, PB);
  k_red2<<<1, 256, 0, stream>>>(PB, g[2], bt[2], invN, aff);
  k_mlp<40, 3><<<gmlp, 256, 0, stream>>>(B, aff, W2[2], b2[2], (float*)d_out, nullptr, N);
}

// Round 10
// 566.066 us; speedup vs baseline: 1.5863x; 1.0097x over previous
//
#include <hip/hip_runtime.h>

#define NN 100000
#define NE 1600000
#define NBK 196       // ceil(100000/512) dst buckets (512 nodes each)
#define CAP 10240     // per-bucket edge capacity
#define EPB 8192      // edges per block in k_bin
#define NWAVES 4096   // wave count for k_mlp (grid-stride, streaming)
#define RB 128        // k_red1 blocks (P partial reduce)
#define SB 256        // k_stat blocks (direct matrix stats)

// ---------------- pass 1: bin edges by dst>>9, packed (src<<9)|dst_local ----------------
__global__ __launch_bounds__(256) void k_bin(const int* __restrict__ src,
                                             const int* __restrict__ dst,
                                             int* __restrict__ gcnt,
                                             unsigned int* __restrict__ binned, int E) {
  __shared__ int bcnt[256];
  const int t = threadIdx.x;
  const int e0 = blockIdx.x * EPB;
  bcnt[t] = 0;
  __syncthreads();
  for (int i = 0; i < EPB; i += 256) {
    int e = e0 + i + t;
    if (e < E) atomicAdd(&bcnt[dst[e] >> 9], 1);
  }
  __syncthreads();
  if (t < NBK) {
    int c = bcnt[t];
    bcnt[t] = c ? atomicAdd(&gcnt[t], c) : 0;
  }
  __syncthreads();
  for (int i = 0; i < EPB; i += 256) {
    int e = e0 + i + t;
    if (e < E) {
      int d = dst[e];
      int b = d >> 9;
      int pos = atomicAdd(&bcnt[b], 1);
      if (pos < CAP) binned[(size_t)b * CAP + pos] = ((unsigned int)src[e] << 9) | (d & 511);
    }
  }
}

// ---------------- pass 2: per-bucket local CSR (block-local writes) ----------------
__global__ __launch_bounds__(512) void k_csr(const unsigned int* __restrict__ binned,
                                             const int* __restrict__ gcnt,
                                             int* __restrict__ rowbeg,
                                             int* __restrict__ rowend,
                                             int* __restrict__ eidx, int N) {
  __shared__ int hist[512];
  __shared__ int cur[512];
  const int t = threadIdx.x;
  const int b = blockIdx.x;
  const size_t base = (size_t)b * CAP;
  int cnt = gcnt[b];
  if (cnt > CAP) cnt = CAP;
  hist[t] = 0;
  __syncthreads();
  for (int e = t; e < cnt; e += 512) atomicAdd(&hist[binned[base + e] & 511], 1);
  __syncthreads();
  const int own = hist[t];
  for (int o = 1; o < 512; o <<= 1) {
    int x = (t >= o) ? hist[t - o] : 0;
    __syncthreads();
    hist[t] += x;
    __syncthreads();
  }
  const int incl = hist[t];
  const int excl = incl - own;
  const int node = b * 512 + t;
  if (node < N) {
    rowbeg[node] = (int)base + excl;
    rowend[node] = (int)base + incl;
  }
  cur[t] = excl;
  __syncthreads();
  for (int e = t; e < cnt; e += 512) {
    unsigned int pk = binned[base + e];
    int pos = atomicAdd(&cur[pk & 511], 1);
    eidx[base + pos] = (int)(pk >> 9);
  }
}

// ------- k_stat: column sum/sumsq of M[N][64] -> PB[SB][128] f64, coalesced + ILP-4 -------
__global__ __launch_bounds__(256) void k_stat(const float* __restrict__ M, int N,
                                              double* __restrict__ PB) {
  const int t = threadIdx.x;
  const int c = t & 63;
  const int rr = t >> 6;  // 0..3
  const int j = blockIdx.x;
  const int STR = SB * 4;  // 1024 rows per sweep
  double s0 = 0, s1 = 0, s2 = 0, s3 = 0, q0 = 0, q1 = 0, q2 = 0, q3 = 0;
  int r = j * 4 + rr;
  for (; r + 3 * STR < N; r += 4 * STR) {
    float v0 = M[(size_t)r * 64 + c];
    float v1 = M[(size_t)(r + STR) * 64 + c];
    float v2 = M[(size_t)(r + 2 * STR) * 64 + c];
    float v3 = M[(size_t)(r + 3 * STR) * 64 + c];
    s0 += v0; q0 = fma((double)v0, (double)v0, q0);
    s1 += v1; q1 = fma((double)v1, (double)v1, q1);
    s2 += v2; q2 = fma((double)v2, (double)v2, q2);
    s3 += v3; q3 = fma((double)v3, (double)v3, q3);
  }
  for (; r < N; r += STR) {
    float v = M[(size_t)r * 64 + c];
    s0 += v; q0 = fma((double)v, (double)v, q0);
  }
  __shared__ double rs[256], rq[256];
  rs[t] = (s0 + s1) + (s2 + s3);
  rq[t] = (q0 + q1) + (q2 + q3);
  __syncthreads();
  if (t < 64)
    PB[(size_t)j * 128 + t] = rs[t] + rs[t + 64] + rs[t + 128] + rs[t + 192];
  else if (t < 128) {
    int c2 = t - 64;
    PB[(size_t)j * 128 + 64 + c2] = rq[c2] + rq[c2 + 64] + rq[c2 + 128] + rq[c2 + 192];
  }
}

// ------- k_red1: P[nblk][128] f32 -> PB[RB][128] f64 (for k_mlp's per-wave partials) -------
__global__ __launch_bounds__(256) void k_red1(const float* __restrict__ P, int nblk,
                                              double* __restrict__ PB) {
  const int t = threadIdx.x;
  const int c = t & 127;
  const int half = t >> 7;  // 0 or 1
  const int j = blockIdx.x;
  const int STR = RB * 2;   // 256 rows per sweep
  double a0 = 0.0, a1 = 0.0, a2 = 0.0, a3 = 0.0;
  int r = j * 2 + half;
  for (; r + 3 * STR < nblk; r += 4 * STR) {
    a0 += (double)P[(size_t)r * 128 + c];
    a1 += (double)P[(size_t)(r + STR) * 128 + c];
    a2 += (double)P[(size_t)(r + 2 * STR) * 128 + c];
    a3 += (double)P[(size_t)(r + 3 * STR) * 128 + c];
  }
  for (; r < nblk; r += STR) a0 += (double)P[(size_t)r * 128 + c];
  double acc = (a0 + a1) + (a2 + a3);
  __shared__ double red[256];
  red[t] = acc;
  __syncthreads();
  if (t < 128) PB[(size_t)j * 128 + t] = red[t] + red[t + 128];
}

// ------- k_red2: finish PB[nrows][128] (ILP-4), emit BN affine LUT -------
__global__ __launch_bounds__(256) void k_red2(const double* __restrict__ PB, int nrows,
                                              const float* __restrict__ g,
                                              const float* __restrict__ bt,
                                              double invN, float* __restrict__ aff) {
  const int t = threadIdx.x;
  const int c = t & 127;
  const int half = t >> 7;
  double a0 = 0.0, a1 = 0.0, a2 = 0.0, a3 = 0.0;
  int j = half;
  for (; j + 6 < nrows; j += 8) {
    a0 += PB[(size_t)j * 128 + c];
    a1 += PB[(size_t)(j + 2) * 128 + c];
    a2 += PB[(size_t)(j + 4) * 128 + c];
    a3 += PB[(size_t)(j + 6) * 128 + c];
  }
  for (; j < nrows; j += 2) a0 += PB[(size_t)j * 128 + c];
  __shared__ double st[256];
  st[t] = (a0 + a1) + (a2 + a3);
  __syncthreads();
  if (t < 128) st[t] = st[t] + st[t + 128];
  __syncthreads();
  if (t < 64) {
    double mu = st[t] * invN;
    double var = st[64 + t] * invN - mu * mu;
    double ai = (double)g[t] / sqrt(var + 1e-5);
    aff[t] = (float)ai;
    aff[64 + t] = (float)((double)bt[t] - ai * mu);
  }
}

__device__ __forceinline__ float rdl(float v, int l) {
  return __int_as_float(__builtin_amdgcn_readlane(__float_as_int(v), l));
}

// ========== fused gather + GEMM1: Z = (gathered,affined A) @ W1 + b1 ==========
// ONE node per WAVE (the proven 63us gather geometry): 4 edge-groups of 16 lanes,
// unroll-2 per group -> 8 row-loads in flight/node; 100k waves. Butterfly shfl gives
// ALL lanes the summed row (lane l holds cols (l&15)*4..+3); readlane GEMM reads
// lanes 0-15 only, so it works from any lane. W staged in LDS once per block
// (start-of-kernel barrier only); no stats, no P write.
template <bool XFORM>
__global__ __launch_bounds__(256) void k_gmm(const float* __restrict__ In,
                                             const float* __restrict__ aff,
                                             const int* __restrict__ rowbeg,
                                             const int* __restrict__ rowend,
                                             const int* __restrict__ eidx,
                                             const float* __restrict__ W,
                                             const float* __restrict__ b,
                                             float* __restrict__ Out, int N) {
  __shared__ float lw[64 * 64];
  const int t = threadIdx.x;
#pragma unroll
  for (int i = 0; i < 4; ++i) {
    int idx = t + i * 256;  // float4 index 0..1023
    *(float4*)(lw + idx * 4) = *(const float4*)(W + idx * 4);
  }
  __syncthreads();

  const int lane = t & 63;
  const int grp = lane >> 4;   // edge group 0..3
  const int c4 = lane & 15;    // float4 column index
  const int node = blockIdx.x * 4 + (t >> 6);
  if (node >= N) return;
  const int beg = rowbeg[node], end = rowend[node];

  float4 s0 = make_float4(0.f, 0.f, 0.f, 0.f);
  float4 s1 = s0;
  if (grp == 0) s0 = *(const float4*)(In + (size_t)node * 64 + c4 * 4);  // self (eps=0)
  int i = beg + grp;
  for (; i + 4 < end; i += 8) {
    const int e0 = eidx[i];
    const int e1 = eidx[i + 4];
    const float4 v0 = *(const float4*)(In + (size_t)e0 * 64 + c4 * 4);
    const float4 v1 = *(const float4*)(In + (size_t)e1 * 64 + c4 * 4);
    s0.x += v0.x; s0.y += v0.y; s0.z += v0.z; s0.w += v0.w;
    s1.x += v1.x; s1.y += v1.y; s1.z += v1.z; s1.w += v1.w;
  }
  if (i < end) {
    const float4 v = *(const float4*)(In + (size_t)eidx[i] * 64 + c4 * 4);
    s0.x += v.x; s0.y += v.y; s0.z += v.z; s0.w += v.w;
  }
  s0.x += s1.x; s0.y += s1.y; s0.z += s1.z; s0.w += s1.w;
#pragma unroll
  for (int off = 16; off < 64; off <<= 1) {  // butterfly: all lanes get the group sum
    s0.x += __shfl_xor(s0.x, off);
    s0.y += __shfl_xor(s0.y, off);
    s0.z += __shfl_xor(s0.z, off);
    s0.w += __shfl_xor(s0.w, off);
  }
  if (XFORM) {
    const float4 fa = *(const float4*)(aff + c4 * 4);
    const float4 fd = *(const float4*)(aff + 64 + c4 * 4);
    const float cnt = (float)(end - beg + 1);
    s0.x = fmaf(fa.x, s0.x, cnt * fd.x);
    s0.y = fmaf(fa.y, s0.y, cnt * fd.y);
    s0.z = fmaf(fa.z, s0.z, cnt * fd.z);
    s0.w = fmaf(fa.w, s0.w, cnt * fd.w);
  }
  const float a4[4] = {s0.x, s0.y, s0.z, s0.w};

  float acc = b[lane];
#pragma unroll
  for (int k = 0; k < 64; ++k)
    acc = fmaf(rdl(a4[k & 3], k >> 2), lw[k * 64 + lane], acc);
  Out[(size_t)node * 64 + lane] = acc;
}

// ========== register-resident GEMM2 (per-wave epilogue, no LDS/barriers) ==========
// MODE 1: relu(out), store, stats(relu)   [inner layers]
// MODE 3: log_softmax(out) -> store        [final layer]
template <int OUTC, int MODE>
__global__ __launch_bounds__(256) void k_mlp(const float* __restrict__ In,
                                             const float* __restrict__ aff,
                                             const float* __restrict__ W,
                                             const float* __restrict__ b,
                                             float* __restrict__ Out,
                                             float* __restrict__ P, int N) {
  const int lane = threadIdx.x & 63;
  const int wid = (blockIdx.x * 256 + threadIdx.x) >> 6;
  const int nw = NWAVES;
  const int G = N >> 2;

  const int cc = (lane < OUTC) ? lane : 0;
  float w[64];
#pragma unroll
  for (int k = 0; k < 64; ++k) w[k] = W[k * OUTC + cc];
  const float bias = b[cc];

  const float4 fa = *(const float4*)(aff + (lane & 15) * 4);
  const float4 fd = *(const float4*)(aff + 64 + (lane & 15) * 4);

  float sc = 0.f, qc = 0.f;

  int g = wid;
  float4 av = make_float4(0.f, 0.f, 0.f, 0.f);
  if (g < G) av = *(const float4*)(In + (size_t)g * 256 + lane * 4);
  for (; g < G; g += nw) {
    const int gn = g + nw;
    float4 nx = make_float4(0.f, 0.f, 0.f, 0.f);
    if (gn < G) nx = *(const float4*)(In + (size_t)gn * 256 + lane * 4);

    float4 v = av;
    v.x = fmaxf(fmaf(fa.x, v.x, fd.x), 0.f);
    v.y = fmaxf(fmaf(fa.y, v.y, fd.y), 0.f);
    v.z = fmaxf(fmaf(fa.z, v.z, fd.z), 0.f);
    v.w = fmaxf(fmaf(fa.w, v.w, fd.w), 0.f);
    const float a4[4] = {v.x, v.y, v.z, v.w};

    float acc0 = bias, acc1 = bias, acc2 = bias, acc3 = bias;
#pragma unroll
    for (int k = 0; k < 64; ++k) {
      const float ak = a4[k & 3];
      const int sl = k >> 2;
      acc0 = fmaf(rdl(ak, sl), w[k], acc0);
      acc1 = fmaf(rdl(ak, 16 + sl), w[k], acc1);
      acc2 = fmaf(rdl(ak, 32 + sl), w[k], acc2);
      acc3 = fmaf(rdl(ak, 48 + sl), w[k], acc3);
    }

    const int r0 = g * 4;
    if (MODE == 1) {
      const float o0 = fmaxf(acc0, 0.f), o1 = fmaxf(acc1, 0.f);
      const float o2 = fmaxf(acc2, 0.f), o3 = fmaxf(acc3, 0.f);
      Out[(size_t)(r0 + 0) * OUTC + lane] = o0;
      Out[(size_t)(r0 + 1) * OUTC + lane] = o1;
      Out[(size_t)(r0 + 2) * OUTC + lane] = o2;
      Out[(size_t)(r0 + 3) * OUTC + lane] = o3;
      sc += o0 + o1 + o2 + o3;
      qc = fmaf(o0, o0, qc);
      qc = fmaf(o1, o1, qc);
      qc = fmaf(o2, o2, qc);
      qc = fmaf(o3, o3, qc);
    } else {  // MODE 3: log_softmax over OUTC cols (lanes >= OUTC masked out)
      float m0 = (lane < OUTC) ? acc0 : -1e30f;
      float m1 = (lane < OUTC) ? acc1 : -1e30f;
      float m2 = (lane < OUTC) ? acc2 : -1e30f;
      float m3 = (lane < OUTC) ? acc3 : -1e30f;
#pragma unroll
      for (int off = 32; off; off >>= 1) {
        m0 = fmaxf(m0, __shfl_xor(m0, off));
        m1 = fmaxf(m1, __shfl_xor(m1, off));
        m2 = fmaxf(m2, __shfl_xor(m2, off));
        m3 = fmaxf(m3, __shfl_xor(m3, off));
      }
      float s0 = (lane < OUTC) ? expf(acc0 - m0) : 0.f;
      float s1 = (lane < OUTC) ? expf(acc1 - m1) : 0.f;
      float s2 = (lane < OUTC) ? expf(acc2 - m2) : 0.f;
      float s3 = (lane < OUTC) ? expf(acc3 - m3) : 0.f;
#pragma unroll
      for (int off = 32; off; off >>= 1) {
        s0 += __shfl_xor(s0, off);
        s1 += __shfl_xor(s1, off);
        s2 += __shfl_xor(s2, off);
        s3 += __shfl_xor(s3, off);
      }
      if (lane < OUTC) {
        Out[(size_t)(r0 + 0) * OUTC + lane] = acc0 - (m0 + logf(s0));
        Out[(size_t)(r0 + 1) * OUTC + lane] = acc1 - (m1 + logf(s1));
        Out[(size_t)(r0 + 2) * OUTC + lane] = acc2 - (m2 + logf(s2));
        Out[(size_t)(r0 + 3) * OUTC + lane] = acc3 - (m3 + logf(s3));
      }
    }
    av = nx;
  }

  if (MODE == 1) {
    P[(size_t)wid * 128 + lane] = sc;
    P[(size_t)wid * 128 + 64 + lane] = qc;
  }
}

extern "C" void kernel_launch(void* const* d_in, const int* in_sizes, int n_in,
                              void* d_out, int out_size, void* d_ws, size_t ws_size,
                              hipStream_t stream) {
  const float* x = (const float*)d_in[0];
  const int* src = (const int*)d_in[1];
  const int* dst = (const int*)d_in[2];
  const float *W1[3], *b1[3], *g[3], *bt[3], *W2[3], *b2[3];
  for (int i = 0; i < 3; ++i) {
    W1[i] = (const float*)d_in[3 + i * 6 + 0];
    b1[i] = (const float*)d_in[3 + i * 6 + 1];
    g[i] = (const float*)d_in[3 + i * 6 + 2];
    bt[i] = (const float*)d_in[3 + i * 6 + 3];
    W2[i] = (const float*)d_in[3 + i * 6 + 4];
    b2[i] = (const float*)d_in[3 + i * 6 + 5];
  }
  const float* bng[2] = {(const float*)d_in[21], (const float*)d_in[23]};
  const float* bnb[2] = {(const float*)d_in[22], (const float*)d_in[24]};

  const int N = NN, E = NE;
  const size_t N64 = (size_t)N * 64;
  const int ggmm = N / 4;            // 25000 blocks (1 node per wave)
  const int gmlp = NWAVES / 4;       // 1024 blocks (grid-stride)

  // workspace layout (~74 MB)
  char* p = (char*)d_ws;
  float* B = (float*)p; p += N64 * 4;            // z buffer
  float* C = (float*)p; p += N64 * 4;            // relu(h) buffer
  int* gcnt = (int*)p; p += 256 * 4;             // bucket counters (memset)
  float* aff = (float*)p; p += 128 * 4;          // BN affine LUT (a[64], d[64])
  float* P = (float*)p; p += (size_t)NWAVES * 128 * 4;  // k_mlp per-wave partials (2MB)
  double* PB = (double*)p; p += (size_t)SB * 128 * 8;   // stats partials (256KB)
  int* rowbeg = (int*)p; p += (size_t)N * 4;
  int* rowend = (int*)p; p += (size_t)N * 4;
  unsigned int* binned = (unsigned int*)p; p += (size_t)NBK * CAP * 4;
  int* eidx = (int*)p; p += (size_t)NBK * CAP * 4;

  const double invN = 1.0 / (double)N;

  hipMemsetAsync(gcnt, 0, 256 * 4, stream);

  // ---- CSR build (bucketed counting sort, block-local writes) ----
  k_bin<<<(E + EPB - 1) / EPB, 256, 0, stream>>>(src, dst, gcnt, binned, E);
  k_csr<<<NBK, 512, 0, stream>>>(binned, gcnt, rowbeg, rowend, eidx, N);

  // ---- layer 0 (input = x, no affine on gather) ----
  k_gmm<false><<<ggmm, 256, 0, stream>>>(x, nullptr, rowbeg, rowend, eidx, W1[0], b1[0], B, N);
  k_stat<<<SB, 256, 0, stream>>>(B, N, PB);
  k_red2<<<1, 256, 0, stream>>>(PB, SB, g[0], bt[0], invN, aff);
  k_mlp<64, 1><<<gmlp, 256, 0, stream>>>(B, aff, W2[0], b2[0], C, P, N);
  k_red1<<<RB, 256, 0, stream>>>(P, NWAVES, PB);
  k_red2<<<1, 256, 0, stream>>>(PB, RB, bng[0], bnb[0], invN, aff);

  // ---- layer 1 ----
  k_gmm<true><<<ggmm, 256, 0, stream>>>(C, aff, rowbeg, rowend, eidx, W1[1], b1[1], B, N);
  k_stat<<<SB, 256, 0, stream>>>(B, N, PB);
  k_red2<<<1, 256, 0, stream>>>(PB, SB, g[1], bt[1], invN, aff);
  k_mlp<64, 1><<<gmlp, 256, 0, stream>>>(B, aff, W2[1], b2[1], C, P, N);
  k_red1<<<RB, 256, 0, stream>>>(P, NWAVES, PB);
  k_red2<<<1, 256, 0, stream>>>(PB, RB, bng[1], bnb[1], invN, aff);

  // ---- layer 2 (final: fused log_softmax) ----
  k_gmm<true><<<ggmm, 256, 0, stream>>>(C, aff, rowbeg, rowend, eidx, W1[2], b1[2], B, N);
  k_stat<<<SB, 256, 0, stream>>>(B, N, PB);
  k_red2<<<1, 256, 0, stream>>>(PB, SB, g[2], bt[2], invN, aff);
  k_mlp<40, 3><<<gmlp, 256, 0, stream>>>(B, aff, W2[2], b2[2], (float*)d_out, nullptr, N);
}